// Round 3
// baseline (479.447 us; speedup 1.0000x reference)
//
#include <hip/hip_runtime.h>
#include <stdint.h>

#define COUT 32

// Phase tables: phase ph covers xs channels [ph*32, ph*32+32) = ys slot T_SRC[ph],
// with element index  l = T_RB + gi*T_SI + gj*T_SJ + gk*T_SK  (reversed scans have
// negative strides and base 32767).
__device__ const int T_SRC[12] = {0,2,1,3,4,6,5,7,8,10,9,11};
__device__ const int T_SI[12]  = {1024,-1024,1024,-1024,1,-1,32,-32,32,-32,1,-1};
__device__ const int T_SJ[12]  = {32,-32,1,-1,1024,-1024,1024,-1024,1,-1,32,-32};
__device__ const int T_SK[12]  = {1,-1,32,-32,32,-32,1,-1,1024,-1024,1024,-1024};
__device__ const int T_RB[12]  = {0,32767,0,32767,0,32767,0,32767,0,32767,0,32767};
__device__ const int T_CB[12]  = {0,0,0,0,1,1,0,0,0,0,1,1};  // 1 = |Si|==1 (class B)

typedef __attribute__((address_space(3))) unsigned int as3u;
typedef __attribute__((address_space(1))) unsigned int as1u;

// Stage one phase (32 channels x 512 positions, 64KB) into LDS buffer.
// Each wave issues exactly 32 global_load_lds dword ops (4 channels x 8 pr).
// LDS is written lane-linear (global_load_lds dest = wave-uniform base + lane*4B);
// the gather permutation lives entirely in the per-lane GLOBAL address.
// Class A (pr = di): lanes cover (dj,dk) -> 8 runs of 8 contiguous floats.
// Class B (pr = dj, storage sigma = dj*64+dk*8+(di^dk^dj)): lanes cover (dk,di)
// -> 8 runs of 8 floats (intra-run permuted, same 32B segment), and the
// compute-side sigma read stays 2-way bank-conflict-free (= free).
__device__ __forceinline__ void stage_phase(
    const float* __restrict__ ys, float* lbuf, int ph,
    int b, int i0, int j0, int k0, int wv, int lhi, int llo)
{
  const int s  = T_SRC[ph];
  const int Si = T_SI[ph], Sj = T_SJ[ph], Sk = T_SK[ph];
  const int rb = T_RB[ph];
  const float* ybase = ys + (((size_t)((b*12 + s)*COUT + wv*4)) << 15);
  if (!T_CB[ph]) {
    const int sc0 = rb + i0*Si + j0*Sj + k0*Sk + lhi*Sj + llo*Sk;
#pragma unroll
    for (int cc = 0; cc < 4; ++cc) {
#pragma unroll
      for (int pr = 0; pr < 8; ++pr) {
        const float* src = ybase + (((size_t)cc) << 15) + (sc0 + pr*Si);
        float* dst = lbuf + (wv*4 + cc)*512 + pr*64;
        __builtin_amdgcn_global_load_lds((const as1u*)src, (as3u*)dst, 4, 0, 0);
      }
    }
  } else {
    const int e   = llo ^ lhi;
    const int sc0 = rb + i0*Si + j0*Sj + k0*Sk + lhi*Sk;
#pragma unroll
    for (int cc = 0; cc < 4; ++cc) {
#pragma unroll
      for (int pr = 0; pr < 8; ++pr) {
        const int diq = e ^ pr;
        const float* src = ybase + (((size_t)cc) << 15) + (sc0 + pr*Sj + diq*Si);
        float* dst = lbuf + (wv*4 + cc)*512 + pr*64;
        __builtin_amdgcn_global_load_lds((const as1u*)src, (as3u*)dst, 4, 0, 0);
      }
    }
  }
}

// Weights are read with block-uniform addresses (w is const __restrict__, o/c4
// compile-time) -> expect s_load_dwordx4 (SMEM, lgkmcnt domain). That keeps the
// vmcnt counting in the main loop exact. If the compiler emits vector loads
// instead, in-order vmcnt retirement still keeps the kernel CORRECT (the
// pipeline just drains early) — check disasm next round.
__device__ __forceinline__ void compute_phase(
    const float* __restrict__ w, const float* lbuf, int ph, int sidx, float* acc)
{
  const float* wp = w + ph*COUT;   // chan = ph*32 + c4*4 + q ; w[o*384 + chan]
#pragma unroll
  for (int c4 = 0; c4 < 8; ++c4) {
    const float x0 = lbuf[(c4*4+0)*512 + sidx];
    const float x1 = lbuf[(c4*4+1)*512 + sidx];
    const float x2 = lbuf[(c4*4+2)*512 + sidx];
    const float x3 = lbuf[(c4*4+3)*512 + sidx];
#pragma unroll
    for (int o = 0; o < COUT; ++o) {
      const float4 wq = *(const float4*)(wp + o*384 + c4*4);  // uniform -> s_load
      acc[o] = __builtin_fmaf(x0, wq.x, acc[o]);
      acc[o] = __builtin_fmaf(x1, wq.y, acc[o]);
      acc[o] = __builtin_fmaf(x2, wq.z, acc[o]);
      acc[o] = __builtin_fmaf(x3, wq.w, acc[o]);
    }
  }
}

__global__ __launch_bounds__(512, 2) void k_fused(
    const float* __restrict__ ys, const float* __restrict__ w,
    const float* __restrict__ cb, float* __restrict__ out)
{
  __shared__ float lds[2][COUT*512];   // 2 x 64KB double buffer (128KB; 1 block/CU)
  const int tid  = threadIdx.x;
  const int lane = tid & 63, wv = tid >> 6;
  const int lhi  = lane >> 3, llo = lane & 7;
  const int bid  = blockIdx.x;
  const int b  = bid >> 6;
  const int i0 = ((bid >> 4) & 3) * 8;
  const int j0 = ((bid >> 2) & 3) * 8;
  const int k0 = (bid & 3) * 8;

  const int di = tid >> 6, dj = (tid >> 3) & 7, dk = tid & 7;  // pos = tid
  const int sidxA = tid;
  const int sidxB = dj*64 + dk*8 + (di ^ dk ^ dj);

  float acc[COUT];
#pragma unroll
  for (int o = 0; o < COUT; ++o) acc[o] = 0.f;

  stage_phase(ys, &lds[0][0], 0, b, i0, j0, k0, wv, lhi, llo);
  for (int ph = 0; ph < 12; ++ph) {       // runtime loop: keep code small
    float* cur = &lds[ph & 1][0];
    if (ph < 11) {
      stage_phase(ys, &lds[(ph + 1) & 1][0], ph + 1, b, i0, j0, k0, wv, lhi, llo);
      // leave the 32 just-issued prefetch loads in flight across the barrier:
      // wait only for the previous phase's 32 (oldest) to land.
      asm volatile("s_waitcnt vmcnt(32)" ::: "memory");
    } else {
      asm volatile("s_waitcnt vmcnt(0)" ::: "memory");
    }
    __builtin_amdgcn_s_barrier();
    const int sidx = T_CB[ph] ? sidxB : sidxA;
    compute_phase(w, cur, ph, sidx, acc);
    asm volatile("" ::: "memory");
    __builtin_amdgcn_s_barrier();         // protect buffer reuse next iteration
  }

  const int gpos = (i0 + di)*1024 + (j0 + dj)*32 + (k0 + dk);
  float* op = out + ((((size_t)b) * COUT) << 15) + gpos;
#pragma unroll
  for (int o = 0; o < COUT; ++o)
    op[((size_t)o) << 15] = acc[o] + cb[o];
}

// Per-(b,o)-row partial sums -> atomicAdd into stats[0..31]=sum, [32..63]=sumsq.
__global__ __launch_bounds__(256, 4) void k_stats(
    const float* __restrict__ out, float* __restrict__ stats)
{
  __shared__ float red[8];
  const int bid = blockIdx.x;          // 128 rows: (b, o)
  const int o   = bid & 31;
  const int tid = threadIdx.x;
  const float* p = out + (((size_t)bid) << 15);
  float s1 = 0.f, s2 = 0.f;
#pragma unroll 4
  for (int it = 0; it < 32; ++it) {
    const float4 v = *(const float4*)(p + it*1024 + tid*4);
    s1 += (v.x + v.y) + (v.z + v.w);
    s2 += (v.x*v.x + v.y*v.y) + (v.z*v.z + v.w*v.w);
  }
#pragma unroll
  for (int off = 32; off > 0; off >>= 1) {
    s1 += __shfl_down(s1, off, 64);
    s2 += __shfl_down(s2, off, 64);
  }
  if ((tid & 63) == 0) { red[(tid >> 6)*2] = s1; red[(tid >> 6)*2 + 1] = s2; }
  __syncthreads();
  if (tid == 0) {
    atomicAdd(&stats[o],      red[0] + red[2] + red[4] + red[6]);
    atomicAdd(&stats[32 + o], red[1] + red[3] + red[5] + red[7]);
  }
}

__global__ __launch_bounds__(256, 4) void k_norm(
    float* __restrict__ out, const float* __restrict__ stats,
    const float* __restrict__ gamma, const float* __restrict__ beta)
{
  const int bid = blockIdx.x;
  const int o   = bid & 31;
  const int tid = threadIdx.x;
  const float invN = 1.0f / 131072.0f;
  const float mean = stats[o] * invN;
  const float var  = stats[32 + o] * invN - mean*mean;
  const float inv  = rsqrtf(var + 1e-5f);
  const float sc   = gamma[o] * inv;
  const float sh   = beta[o] - mean * sc;
  float* p = out + (((size_t)bid) << 15);
#pragma unroll 4
  for (int it = 0; it < 32; ++it) {
    float4 v = *(const float4*)(p + it*1024 + tid*4);
    v.x = __builtin_fmaf(v.x, sc, sh);
    v.y = __builtin_fmaf(v.y, sc, sh);
    v.z = __builtin_fmaf(v.z, sc, sh);
    v.w = __builtin_fmaf(v.w, sc, sh);
    *(float4*)(p + it*1024 + tid*4) = v;
  }
}

extern "C" void kernel_launch(void* const* d_in, const int* in_sizes, int n_in,
                              void* d_out, int out_size, void* d_ws, size_t ws_size,
                              hipStream_t stream)
{
  const float* ys    = (const float*)d_in[0];
  const float* w     = (const float*)d_in[1];
  const float* cb    = (const float*)d_in[2];
  const float* gamma = (const float*)d_in[3];
  const float* beta  = (const float*)d_in[4];
  float* out   = (float*)d_out;
  float* stats = (float*)d_ws;

  hipMemsetAsync(stats, 0, 64 * sizeof(float), stream);
  hipLaunchKernelGGL(k_fused, dim3(256), dim3(512), 0, stream, ys, w, cb, out);
  hipLaunchKernelGGL(k_stats, dim3(128), dim3(256), 0, stream, out, stats);
  hipLaunchKernelGGL(k_norm,  dim3(128), dim3(256), 0, stream, out, stats, gamma, beta);
}

// Round 4
// 424.454 us; speedup vs baseline: 1.1296x; 1.1296x over previous
//
#include <hip/hip_runtime.h>
#include <stdint.h>

#define COUT 32

typedef __attribute__((address_space(3))) unsigned int as3u;
typedef __attribute__((address_space(1))) unsigned int as1u;

// Per-phase parameters, branch-light uniform arithmetic (no memory tables).
// Phase ph covers xs channels [ph*32,ph*32+32) = ys slot src, element index
// l = rb + gi*Si + gj*Sj + gk*Sk. Verified against the reference _merge:
//  g0 (xs_i): Si=1024; (Sj,Sk) = v? (1,32):(32,1)
//  g1 (xs_j): Sj=1024; (Sk,Si) = v? (1,32):(32,1)
//  g2 (xs_k): Sk=1024; (Si,Sj) = v? (1,32):(32,1)
// neg (reversed scan): all strides negated, rb=32767.  src within group {0,2,1,3}.
__device__ __forceinline__ void phase_params(int ph, int& src, int& Si, int& Sj, int& Sk,
                                             int& rb, int& cb) {
  const int g = ph >> 2, q = ph & 3;
  const int neg = q & 1, v = q >> 1;
  src = (ph & ~3) | (neg << 1) | v;
  rb = neg ? 32767 : 0;
  const int sA = v ? 1 : 32, sB = v ? 32 : 1;
  if (g == 0)      { Si = 1024; Sj = sA; Sk = sB; }
  else if (g == 1) { Sj = 1024; Sk = sA; Si = sB; }
  else             { Sk = 1024; Si = sA; Sj = sB; }
  if (neg) { Si = -Si; Sj = -Sj; Sk = -Sk; }
  cb = ((g == 1) && (v == 0)) || ((g == 2) && (v == 1));  // |Si|==1 phases
}

__device__ __forceinline__ int phase_cb(int ph) {
  const int g = ph >> 2, v = (ph >> 1) & 1;
  return ((g == 1) && (v == 0)) || ((g == 2) && (v == 1));
}

// Stage one phase's x-tile (32 ch x 512 pos, 64KB) into LDS. 32 dword
// global_load_lds per wave; LDS dest lane-linear, permutation on global addr.
// Class A: stor = di*64+dj*8+dk (pr=di, lanes=(dj,dk)).
// Class B (|Si|==1): stor sigma = dj*64+dk*8+(di^dk^dj) (pr=dj, lanes=(dk,diq)).
__device__ __forceinline__ void stage_phase(
    const float* __restrict__ ys, float* lbuf, int ph,
    int b, int i0, int j0, int k0, int wv, int lhi, int llo)
{
  int s, Si, Sj, Sk, rb, cb;
  phase_params(ph, s, Si, Sj, Sk, rb, cb);
  const float* ybase = ys + (((size_t)((b*12 + s)*COUT + wv*4)) << 15);
  if (!cb) {
    const int sc0 = rb + i0*Si + j0*Sj + k0*Sk + lhi*Sj + llo*Sk;
#pragma unroll
    for (int cc = 0; cc < 4; ++cc) {
#pragma unroll
      for (int pr = 0; pr < 8; ++pr) {
        const float* src = ybase + (((size_t)cc) << 15) + (sc0 + pr*Si);
        float* dst = lbuf + (wv*4 + cc)*512 + pr*64;
        __builtin_amdgcn_global_load_lds((const as1u*)src, (as3u*)dst, 4, 0, 0);
      }
    }
  } else {
    const int e   = llo ^ lhi;
    const int sc0 = rb + i0*Si + j0*Sj + k0*Sk + lhi*Sk;
#pragma unroll
    for (int cc = 0; cc < 4; ++cc) {
#pragma unroll
      for (int pr = 0; pr < 8; ++pr) {
        const int diq = e ^ pr;
        const float* src = ybase + (((size_t)cc) << 15) + (sc0 + pr*Sj + diq*Si);
        float* dst = lbuf + (wv*4 + cc)*512 + pr*64;
        __builtin_amdgcn_global_load_lds((const as1u*)src, (as3u*)dst, 4, 0, 0);
      }
    }
  }
}

// Stage the phase's 4KB weight slice w[o*384 + ph*32 + c] (o,c in 32x32) into
// wbuf[o*32+c]. 4 dwordx4 global_load_lds issued by wave 0 only. Lane-linear:
// instr q, lane l -> o = q*8 + (l>>3), c = (l&7)*4 .. +3. 16B-aligned (384,32,4
// all give multiples of 16B).
__device__ __forceinline__ void stage_weights(const float* __restrict__ w, float* wbuf,
                                              int ph, int lane) {
  const float* src0 = w + ph*32 + (lane >> 3)*384 + (lane & 7)*4;
#pragma unroll
  for (int qq = 0; qq < 4; ++qq) {
    __builtin_amdgcn_global_load_lds((const as1u*)(src0 + qq*8*384),
                                     (as3u*)(wbuf + qq*256), 16, 0, 0);
  }
}

// Weights now come from LDS via same-address broadcast ds_read_b128 (free),
// removing the 256 global-latency loads per thread per phase that serialized r3.
__device__ __forceinline__ void compute_phase(
    const float* wbuf, const float* lbuf, int sidx, float* acc)
{
#pragma unroll
  for (int c4 = 0; c4 < 8; ++c4) {
    const float x0 = lbuf[(c4*4+0)*512 + sidx];
    const float x1 = lbuf[(c4*4+1)*512 + sidx];
    const float x2 = lbuf[(c4*4+2)*512 + sidx];
    const float x3 = lbuf[(c4*4+3)*512 + sidx];
#pragma unroll
    for (int o = 0; o < COUT; ++o) {
      const float4 wq = *(const float4*)(wbuf + o*32 + c4*4);  // broadcast
      acc[o] = __builtin_fmaf(x0, wq.x, acc[o]);
      acc[o] = __builtin_fmaf(x1, wq.y, acc[o]);
      acc[o] = __builtin_fmaf(x2, wq.z, acc[o]);
      acc[o] = __builtin_fmaf(x3, wq.w, acc[o]);
    }
  }
}

__global__ __launch_bounds__(512, 2) void k_fused(
    const float* __restrict__ ys, const float* __restrict__ w,
    const float* __restrict__ cb, float* __restrict__ out)
{
  __shared__ float lds[2][COUT*512];   // 2 x 64KB x-tile double buffer
  __shared__ float wlds[2][COUT*32];   // 2 x 4KB weight-slice double buffer
  const int tid  = threadIdx.x;
  const int lane = tid & 63, wv = tid >> 6;
  const int lhi  = lane >> 3, llo = lane & 7;
  const int bid  = blockIdx.x;
  const int b  = bid >> 6;
  const int i0 = ((bid >> 4) & 3) * 8;
  const int j0 = ((bid >> 2) & 3) * 8;
  const int k0 = (bid & 3) * 8;

  const int di = tid >> 6, dj = (tid >> 3) & 7, dk = tid & 7;  // pos = tid
  const int sidxA = tid;
  const int sidxB = dj*64 + dk*8 + (di ^ dk ^ dj);

  float acc[COUT];
#pragma unroll
  for (int o = 0; o < COUT; ++o) acc[o] = 0.f;

  stage_phase(ys, &lds[0][0], 0, b, i0, j0, k0, wv, lhi, llo);
  if (wv == 0) stage_weights(w, &wlds[0][0], 0, lane);
  for (int ph = 0; ph < 12; ++ph) {
    const float* cur  = &lds[ph & 1][0];
    const float* wcur = &wlds[ph & 1][0];
    if (ph < 11) {
      stage_phase(ys, &lds[(ph + 1) & 1][0], ph + 1, b, i0, j0, k0, wv, lhi, llo);
      if (wv == 0) {
        stage_weights(w, &wlds[(ph + 1) & 1][0], ph + 1, lane);
        // wave 0 has 36 loads in flight for phase ph+1; wait out phase ph's 36.
        asm volatile("s_waitcnt vmcnt(36)" ::: "memory");
      } else {
        asm volatile("s_waitcnt vmcnt(32)" ::: "memory");
      }
    } else {
      asm volatile("s_waitcnt vmcnt(0)" ::: "memory");
    }
    __builtin_amdgcn_s_barrier();
    const int sidx = phase_cb(ph) ? sidxB : sidxA;
    compute_phase(wcur, cur, sidx, acc);
    asm volatile("" ::: "memory");
    __builtin_amdgcn_s_barrier();         // protect buffer reuse next iteration
  }

  const int gpos = (i0 + di)*1024 + (j0 + dj)*32 + (k0 + dk);
  float* op = out + ((((size_t)b) * COUT) << 15) + gpos;
#pragma unroll
  for (int o = 0; o < COUT; ++o)
    op[((size_t)o) << 15] = acc[o] + cb[o];
}

// 512 blocks (2/CU): block = (row 0..127, quarter 0..3); 8 float4-iters/thread.
__global__ __launch_bounds__(256, 4) void k_stats(
    const float* __restrict__ out, float* __restrict__ stats)
{
  __shared__ float red[8];
  const int row = blockIdx.x >> 2, quad = blockIdx.x & 3;
  const int o   = row & 31;
  const int tid = threadIdx.x;
  const float* p = out + (((size_t)row) << 15) + quad * 8192;
  float s1 = 0.f, s2 = 0.f;
#pragma unroll
  for (int it = 0; it < 8; ++it) {
    const float4 v = *(const float4*)(p + it*1024 + tid*4);
    s1 += (v.x + v.y) + (v.z + v.w);
    s2 += (v.x*v.x + v.y*v.y) + (v.z*v.z + v.w*v.w);
  }
#pragma unroll
  for (int off = 32; off > 0; off >>= 1) {
    s1 += __shfl_down(s1, off, 64);
    s2 += __shfl_down(s2, off, 64);
  }
  if ((tid & 63) == 0) { red[(tid >> 6)*2] = s1; red[(tid >> 6)*2 + 1] = s2; }
  __syncthreads();
  if (tid == 0) {
    atomicAdd(&stats[o],      red[0] + red[2] + red[4] + red[6]);
    atomicAdd(&stats[32 + o], red[1] + red[3] + red[5] + red[7]);
  }
}

__global__ __launch_bounds__(256, 4) void k_norm(
    float* __restrict__ out, const float* __restrict__ stats,
    const float* __restrict__ gamma, const float* __restrict__ beta)
{
  const int row = blockIdx.x >> 2, quad = blockIdx.x & 3;
  const int o   = row & 31;
  const int tid = threadIdx.x;
  const float invN = 1.0f / 131072.0f;
  const float mean = stats[o] * invN;
  const float var  = stats[32 + o] * invN - mean*mean;
  const float inv  = rsqrtf(var + 1e-5f);
  const float sc   = gamma[o] * inv;
  const float sh   = beta[o] - mean * sc;
  float* p = out + (((size_t)row) << 15) + quad * 8192;
#pragma unroll
  for (int it = 0; it < 8; ++it) {
    float4 v = *(const float4*)(p + it*1024 + tid*4);
    v.x = __builtin_fmaf(v.x, sc, sh);
    v.y = __builtin_fmaf(v.y, sc, sh);
    v.z = __builtin_fmaf(v.z, sc, sh);
    v.w = __builtin_fmaf(v.w, sc, sh);
    *(float4*)(p + it*1024 + tid*4) = v;
  }
}

extern "C" void kernel_launch(void* const* d_in, const int* in_sizes, int n_in,
                              void* d_out, int out_size, void* d_ws, size_t ws_size,
                              hipStream_t stream)
{
  const float* ys    = (const float*)d_in[0];
  const float* w     = (const float*)d_in[1];
  const float* cb    = (const float*)d_in[2];
  const float* gamma = (const float*)d_in[3];
  const float* beta  = (const float*)d_in[4];
  float* out   = (float*)d_out;
  float* stats = (float*)d_ws;

  hipMemsetAsync(stats, 0, 64 * sizeof(float), stream);
  hipLaunchKernelGGL(k_fused, dim3(256), dim3(512), 0, stream, ys, w, cb, out);
  hipLaunchKernelGGL(k_stats, dim3(512), dim3(256), 0, stream, out, stats);
  hipLaunchKernelGGL(k_norm,  dim3(512), dim3(256), 0, stream, out, stats, gamma, beta);
}